// Round 21
// baseline (286.458 us; speedup 1.0000x reference)
//
#include <hip/hip_runtime.h>
#include <math.h>

// Pipeline (d_out scratch: Wf fp16 1.5MB only):
//   k0 cvt_w_frag:  w_qkv fp32 -> Wf fp16 in FRAGMENT order
//   k1 gemm:        qkv16 = fp16(A @ W^T + bias) in d_ws.
//                   r21: A staged as FP32 via global_load_lds (cvt_a pass
//                   ELIMINATED); per-fragment cvt_pkrtz after ds_read.
//                   r20 passive-drain sync (no vmcnt at steady barriers).
//   k2 scramble:    qkv16 -> out fp32 (r18-verified)

typedef _Float16 half8 __attribute__((ext_vector_type(8)));
typedef _Float16 half4 __attribute__((ext_vector_type(4)));
typedef __fp16 fp16x2 __attribute__((ext_vector_type(2)));
typedef float f32x4 __attribute__((ext_vector_type(4)));

__device__ __forceinline__ half8 pk8(const float4 x, const float4 y) {
    fp16x2 a = __builtin_amdgcn_cvt_pkrtz(x.x, x.y);
    fp16x2 b = __builtin_amdgcn_cvt_pkrtz(x.z, x.w);
    fp16x2 c = __builtin_amdgcn_cvt_pkrtz(y.x, y.y);
    fp16x2 d = __builtin_amdgcn_cvt_pkrtz(y.z, y.w);
    half8 r;
    r[0] = (_Float16)a[0]; r[1] = (_Float16)a[1];
    r[2] = (_Float16)b[0]; r[3] = (_Float16)b[1];
    r[4] = (_Float16)c[0]; r[5] = (_Float16)c[1];
    r[6] = (_Float16)d[0]; r[7] = (_Float16)d[1];
    return r;
}

__device__ __forceinline__ void gload_lds16(const void* g, void* l) {
    __builtin_amdgcn_global_load_lds(
        (const __attribute__((address_space(1))) unsigned int*)g,
        (__attribute__((address_space(3))) unsigned int*)l, 16, 0, 0);
}

// ---------------------------------------------------------------------------
// k0: W fp32 [1536,512] -> Wf fp16 fragment-ordered (98304 threads)
// ---------------------------------------------------------------------------
__global__ __launch_bounds__(256) void cvt_w_frag(
    const float* __restrict__ W, _Float16* __restrict__ Wf)
{
    const int gid  = blockIdx.x * 256 + threadIdx.x;   // 0..98303
    const int lane = gid & 63;
    const int nf   = (gid >> 6) & 3;
    const int ks   = (gid >> 8) & 15;
    const int ntw  = gid >> 12;                        // 0..23
    const float* src =
        W + (size_t)(ntw * 64 + nf * 16 + (lane & 15)) * 512 +
        ks * 32 + (lane >> 4) * 8;
    const float4 x = *reinterpret_cast<const float4*>(src);
    const float4 y = *reinterpret_cast<const float4*>(src + 4);
    *reinterpret_cast<half8*>(Wf + (size_t)gid * 8) = pk8(x, y);
}

// ---------------------------------------------------------------------------
// k1: C16[65536,1536] = fp16(A @ W^T + bias).  BM=BN=128, BK=32, 4 waves.
// A: FP32 tiles 128x32 (16 KB) via global_load_lds, 3-buffer rotation.
// Swizzle (128B rows = 8 x 16B chunks): source chunk c = (lane&7)^(lane>>3);
// read phys chunk = (2kq+h) ^ (r&7)  -> uniform 8 lanes / 16B-slot.
// W: fragment-ordered global loads (L2), 2 named sets, passive drain (r20).
// ---------------------------------------------------------------------------
__global__ __launch_bounds__(256, 3) void gemm_qkv_a32(
    const float* __restrict__ A, const _Float16* __restrict__ Wf,
    const float* __restrict__ bias, _Float16* __restrict__ C)
{
    __shared__ __align__(16) float ldsf[12288];     // 3 x 16 KB

    const int lin = blockIdx.x;                     // 6144 blocks, %8==0
    const int swz = (lin & 7) * 768 + (lin >> 3);
    const int nt = swz % 12, mt = swz / 12;         // nt fastest: A L2-reuse
    const int row0 = mt * 128, col0 = nt * 128;

    const int tid = threadIdx.x, wid = tid >> 6, lane = tid & 63;
    const int wm = wid >> 1, wn = wid & 1, l15 = lane & 15, kq = lane >> 4;

    // A staging: wave wid owns 1KB segments {wid*4 .. wid*4+3} of each tile.
    // Lane j writes 16B linearly at seg*1024 + j*16; tile slot row =
    // seg*8 + (j>>3), phys chunk = j&7; source holds logical chunk
    // (j&7) ^ (row&7) = (j&7) ^ (j>>3).
    const int s0 = wid * 4;
    const int cA = (lane & 7) ^ (lane >> 3);        // logical chunk in source
    const float* ga[4];
#pragma unroll
    for (int i = 0; i < 4; ++i) {
        const int rA = (s0 + i) * 8 + (lane >> 3);
        ga[i] = A + (size_t)(row0 + rA) * 512 + cA * 4;
    }

    // W fragment base for this thread: frags at wfb + (ks*4+nf)*512
    const _Float16* wfb = Wf + (size_t)(nt * 2 + wn) * 32768 + lane * 8;

    f32x4 acc[4][4];
#pragma unroll
    for (int i = 0; i < 4; ++i)
#pragma unroll
        for (int j = 0; j < 4; ++j) acc[i][j] = (f32x4)0.f;

    half8 wfa[4], wfb_[4];   // two named W-frag sets (static indices only)

#define STAGE_A(KB, BUF)                                                       \
    do {                                                                       \
        float* bdst = ldsf + (BUF) * 4096;                                     \
        gload_lds16(ga[0] + (KB), bdst + (s0 + 0) * 256);                      \
        gload_lds16(ga[1] + (KB), bdst + (s0 + 1) * 256);                      \
        gload_lds16(ga[2] + (KB), bdst + (s0 + 2) * 256);                      \
        gload_lds16(ga[3] + (KB), bdst + (s0 + 3) * 256);                      \
    } while (0)

#define LOAD_W(DST, KS)                                                        \
    do {                                                                       \
        _Pragma("unroll")                                                      \
        for (int nf = 0; nf < 4; ++nf)                                         \
            DST[nf] = *reinterpret_cast<const half8*>(                         \
                wfb + (KS) * 2048 + nf * 512);                                 \
    } while (0)

#define FRAG_MFMA(BC, WU)                                                      \
    do {                                                                       \
        half8 ah[4];                                                           \
        _Pragma("unroll")                                                      \
        for (int mf = 0; mf < 4; ++mf) {                                       \
            const int r   = wm * 64 + mf * 16 + l15;                           \
            const int ph0 = ((2 * kq + 0) ^ (r & 7)) * 4;                      \
            const int ph1 = ((2 * kq + 1) ^ (r & 7)) * 4;                      \
            const float4 a0 = *reinterpret_cast<const float4*>(                \
                (BC) + r * 32 + ph0);                                          \
            const float4 a1 = *reinterpret_cast<const float4*>(                \
                (BC) + r * 32 + ph1);                                          \
            ah[mf] = pk8(a0, a1);                                              \
        }                                                                      \
        _Pragma("unroll")                                                      \
        for (int nf = 0; nf < 4; ++nf)                                         \
            _Pragma("unroll")                                                  \
            for (int mf = 0; mf < 4; ++mf)                                     \
                acc[mf][nf] = __builtin_amdgcn_mfma_f32_16x16x32_f16(          \
                    ah[mf], WU[nf], acc[mf][nf], 0, 0, 0);                     \
    } while (0)

// STEP(T): stage A tile T+2, pin issue order, load other W set with tile
// T+1, compute tile T. Barrier carries NO vmcnt: this FRAG's W(T)-register
// wait (in-order vmcnt retirement) already drained A(T+1), issued earlier.
#define STEP(T, WU, WL)                                                        \
    do {                                                                       \
        const int t2 = ((T) + 2 < 16) ? (T) + 2 : 15;                          \
        const int t1 = ((T) + 1 < 16) ? (T) + 1 : 15;                          \
        int sb = cb + 2; if (sb >= 3) sb -= 3;                                 \
        STAGE_A(t2 * 32, sb);                                                  \
        __builtin_amdgcn_sched_barrier(0);   /* pin: A glds before W loads */  \
        LOAD_W(WL, t1);                                                        \
        FRAG_MFMA(ldsf + cb * 4096, WU);                                       \
        __builtin_amdgcn_sched_barrier(0);                                     \
        __builtin_amdgcn_s_barrier();                                          \
        __builtin_amdgcn_sched_barrier(0);                                     \
        cb = (cb == 2) ? 0 : cb + 1;                                           \
    } while (0)

    // prologue: A tiles 0,1 -> bufs 0,1; W set a <- tile 0; drain A(0) only
    STAGE_A(0, 0);
    STAGE_A(32, 1);
    __builtin_amdgcn_sched_barrier(0);
    LOAD_W(wfa, 0);
    asm volatile("s_waitcnt vmcnt(8)" ::: "memory");   // A(0)'s 4 glds landed
    __builtin_amdgcn_sched_barrier(0);
    __builtin_amdgcn_s_barrier();
    __builtin_amdgcn_sched_barrier(0);

    int cb = 0;
#pragma unroll 1
    for (int t = 0; t < 16; t += 2) {
        STEP(t,     wfa, wfb_);
        STEP(t + 1, wfb_, wfa);
    }
#undef STEP
#undef FRAG_MFMA
#undef LOAD_W
#undef STAGE_A

    // ---- epilogue: per-wave LDS transpose -> fp16 half4 stores.
    // __syncthreads() fences between scatter and gather (r17-verified).
    float* wbase = ldsf + wid * 1088;
    const float4 bv4 = *reinterpret_cast<const float4*>(
        &bias[col0 + wn * 64 + l15 * 4]);

#pragma unroll
    for (int mf = 0; mf < 4; ++mf) {
#pragma unroll
        for (int nf = 0; nf < 4; ++nf)
#pragma unroll
            for (int j = 0; j < 4; ++j)
                wbase[(kq * 4 + j) * 68 + nf * 16 + l15] = acc[mf][nf][j];
        __syncthreads();   // writes visible before cross-lane reads
#pragma unroll
        for (int i = 0; i < 4; ++i) {
            const int r16 = i * 4 + kq;
            float4 v = *reinterpret_cast<float4*>(wbase + r16 * 68 + l15 * 4);
            half4 h;
            h[0] = (_Float16)(v.x + bv4.x);   // RNE
            h[1] = (_Float16)(v.y + bv4.y);
            h[2] = (_Float16)(v.z + bv4.z);
            h[3] = (_Float16)(v.w + bv4.w);
            const int r = row0 + wm * 64 + mf * 16 + r16;
            *reinterpret_cast<half4*>(
                &C[(size_t)r * 1536 + col0 + wn * 64 + l15 * 4]) = h;
        }
        __syncthreads();   // reads done before next mf's scatter overwrites
    }
}

// ---------------------------------------------------------------------------
// k2: scrambled elementwise softmax; qkv FP16 (r18-verified)
// ---------------------------------------------------------------------------
__global__ __launch_bounds__(256) void attn_scramble(
    const _Float16* __restrict__ qkv, float* __restrict__ out)
{
    __shared__ float Ks[64][68];    // [hwlo][d'], rows 272B (16B-aligned)
    const int bid = blockIdx.x;
    const int hw6 = bid & 63;
    const int n   = (bid >> 6) & 7;
    const int b   = bid >> 9;
    const int kn  = (n + 7) & 7;
    const int t   = threadIdx.x;
    {
        const int lx = t & 7;       // 8 lanes x half8 cover one d'-row (64)
        const int rp = t >> 3;      // 32 d'-rows per pass
#pragma unroll
        for (int p = 0; p < 2; ++p) {
            const int dp = p * 32 + rp;
            const half8 kv = *reinterpret_cast<const half8*>(
                &qkv[(size_t)(b * 4096 + dp * 64 + hw6) * 1536 + 512 +
                     kn * 64 + lx * 8]);
#pragma unroll
            for (int e = 0; e < 8; ++e)
                Ks[lx * 8 + e][dp] = (float)kv[e];
        }
    }
    __syncthreads();
    const int row = t >> 2;
    const int tl  = t & 3;
    const size_t rbase = (size_t)(b * 4096 + hw6 * 64 + row) * 1536;
    float s[16];
    {
        const _Float16* qp = qkv + rbase + n * 64 + tl * 16;
        const half8 q0 = *reinterpret_cast<const half8*>(qp);
        const half8 q1 = *reinterpret_cast<const half8*>(qp + 8);
        float q[16], kk[16];
#pragma unroll
        for (int e = 0; e < 8; ++e) {
            q[e] = (float)q0[e];
            q[8 + e] = (float)q1[e];
        }
#pragma unroll
        for (int u = 0; u < 4; ++u)
            *reinterpret_cast<float4*>(&kk[u * 4]) =
                *reinterpret_cast<const float4*>(&Ks[row][tl * 16 + u * 4]);
        float m = -1e30f;
#pragma unroll
        for (int u = 0; u < 16; ++u) {
            s[u] = 0.125f * q[u] * kk[u];
            m = fmaxf(m, s[u]);
        }
        m = fmaxf(m, __shfl_xor(m, 1));
        m = fmaxf(m, __shfl_xor(m, 2));
        float sum = 0.f;
#pragma unroll
        for (int u = 0; u < 16; ++u) {
            s[u] = __expf(s[u] - m);
            sum += s[u];
        }
        sum += __shfl_xor(sum, 1);
        sum += __shfl_xor(sum, 2);
        const float inv = 1.0f / sum;
#pragma unroll
        for (int u = 0; u < 16; ++u) s[u] *= inv;
    }
    const _Float16* vp = qkv + rbase + 1024 + kn * 64 + tl * 16;
    const half8 v0 = *reinterpret_cast<const half8*>(vp);
    const half8 v1 = *reinterpret_cast<const half8*>(vp + 8);
    const int vb = b >> 3, fr = b & 7;
    float* op = out +
        ((size_t)(((vb * 8 + (hw6 >> 3)) * 64 + ((hw6 & 7) * 8 + (row >> 3))) * 64 +
                  ((row & 7) * 8 + n)) * 512) + fr * 64 + tl * 16;
    float4 o0, o1, o2, o3;
    o0.x = s[0]  * (float)v0[0]; o0.y = s[1]  * (float)v0[1];
    o0.z = s[2]  * (float)v0[2]; o0.w = s[3]  * (float)v0[3];
    o1.x = s[4]  * (float)v0[4]; o1.y = s[5]  * (float)v0[5];
    o1.z = s[6]  * (float)v0[6]; o1.w = s[7]  * (float)v0[7];
    o2.x = s[8]  * (float)v1[0]; o2.y = s[9]  * (float)v1[1];
    o2.z = s[10] * (float)v1[2]; o2.w = s[11] * (float)v1[3];
    o3.x = s[12] * (float)v1[4]; o3.y = s[13] * (float)v1[5];
    o3.z = s[14] * (float)v1[6]; o3.w = s[15] * (float)v1[7];
    *reinterpret_cast<float4*>(op)      = o0;
    *reinterpret_cast<float4*>(op + 4)  = o1;
    *reinterpret_cast<float4*>(op + 8)  = o2;
    *reinterpret_cast<float4*>(op + 12) = o3;
}

// ---------------------------------------------------------------------------
extern "C" void kernel_launch(void* const* d_in, const int* in_sizes, int n_in,
                              void* d_out, int out_size, void* d_ws, size_t ws_size,
                              hipStream_t stream) {
    const float* hs = (const float*)d_in[0];  // [65536,512]
    const float* w  = (const float*)d_in[1];  // [1536,512]
    const float* bq = (const float*)d_in[2];  // [1536]
    float* out = (float*)d_out;
    _Float16* qkv = (_Float16*)d_ws;          // 201,326,592 B (fits)

    // d_out as scratch: Wf (1,572,864 B)
    _Float16* Wf = (_Float16*)d_out;

    cvt_w_frag<<<384, 256, 0, stream>>>(w, Wf);
    gemm_qkv_a32<<<6144, 256, 0, stream>>>(hs, Wf, bq, qkv);
    attn_scramble<<<8192, 256, 0, stream>>>(qkv, out);
}

// Round 22
// 233.085 us; speedup vs baseline: 1.2290x; 1.2290x over previous
//
#include <hip/hip_runtime.h>
#include <math.h>

// Pipeline (d_out doubles as scratch: Ah fp16 67MB + Wf fp16 1.5MB):
//   k0 cvt_fp16(A):  A fp32 [65536,512] -> Ah fp16 (row-major) in d_out
//   k0b cvt_w_frag:  w_qkv fp32 -> Wf fp16 in FRAGMENT order
//   k1 gemm:         qkv16 = fp16(Ah @ W^T + bias) in d_ws.
//                    r20 passive-drain structure (best measured: 140us) +
//                    r22: s_setprio(1) around MFMA cluster (T5).
//   k2 scramble:     qkv16 -> out fp32 (r18-verified)

typedef _Float16 half8 __attribute__((ext_vector_type(8)));
typedef _Float16 half4 __attribute__((ext_vector_type(4)));
typedef __fp16 fp16x2 __attribute__((ext_vector_type(2)));
typedef float f32x4 __attribute__((ext_vector_type(4)));

__device__ __forceinline__ half8 pk8(const float4 x, const float4 y) {
    fp16x2 a = __builtin_amdgcn_cvt_pkrtz(x.x, x.y);
    fp16x2 b = __builtin_amdgcn_cvt_pkrtz(x.z, x.w);
    fp16x2 c = __builtin_amdgcn_cvt_pkrtz(y.x, y.y);
    fp16x2 d = __builtin_amdgcn_cvt_pkrtz(y.z, y.w);
    half8 r;
    r[0] = (_Float16)a[0]; r[1] = (_Float16)a[1];
    r[2] = (_Float16)b[0]; r[3] = (_Float16)b[1];
    r[4] = (_Float16)c[0]; r[5] = (_Float16)c[1];
    r[6] = (_Float16)d[0]; r[7] = (_Float16)d[1];
    return r;
}

__device__ __forceinline__ void gload_lds16(const void* g, void* l) {
    __builtin_amdgcn_global_load_lds(
        (const __attribute__((address_space(1))) unsigned int*)g,
        (__attribute__((address_space(3))) unsigned int*)l, 16, 0, 0);
}

// ---------------------------------------------------------------------------
// k0: streaming fp32 -> fp16
// ---------------------------------------------------------------------------
__global__ __launch_bounds__(256) void cvt_fp16(
    const float* __restrict__ src, _Float16* __restrict__ dst)
{
    const size_t i = (size_t)blockIdx.x * 256 + threadIdx.x;
    const float4 x = *reinterpret_cast<const float4*>(src + i * 8);
    const float4 y = *reinterpret_cast<const float4*>(src + i * 8 + 4);
    *reinterpret_cast<half8*>(dst + i * 8) = pk8(x, y);
}

// ---------------------------------------------------------------------------
// k0b: W fp32 [1536,512] -> Wf fp16 fragment-ordered (98304 threads)
// ---------------------------------------------------------------------------
__global__ __launch_bounds__(256) void cvt_w_frag(
    const float* __restrict__ W, _Float16* __restrict__ Wf)
{
    const int gid  = blockIdx.x * 256 + threadIdx.x;   // 0..98303
    const int lane = gid & 63;
    const int nf   = (gid >> 6) & 3;
    const int ks   = (gid >> 8) & 15;
    const int ntw  = gid >> 12;                        // 0..23
    const float* src =
        W + (size_t)(ntw * 64 + nf * 16 + (lane & 15)) * 512 +
        ks * 32 + (lane >> 4) * 8;
    const float4 x = *reinterpret_cast<const float4*>(src);
    const float4 y = *reinterpret_cast<const float4*>(src + 4);
    *reinterpret_cast<half8*>(Wf + (size_t)gid * 8) = pk8(x, y);
}

// ---------------------------------------------------------------------------
// k1: C16[65536,1536] = fp16(Ah @ W^T + bias).  BM=BN=128, BK=32, 4 waves.
// LDS: 3 x 8 KB A-buffers (rotation); epilogue reuses first 17 KB.
// Swizzle: chunk c of row r at phys c ^ ((r>>1)&3), XOR on GLOBAL src.
// ---------------------------------------------------------------------------
__global__ __launch_bounds__(256, 4) void gemm_qkv_wf(
    const _Float16* __restrict__ Ah, const _Float16* __restrict__ Wf,
    const float* __restrict__ bias, _Float16* __restrict__ C)
{
    __shared__ __align__(16) _Float16 lds[12288];   // 3 x 8 KB

    const int lin = blockIdx.x;                     // 6144 blocks, %8==0
    const int swz = (lin & 7) * 768 + (lin >> 3);
    const int nt = swz % 12, mt = swz / 12;         // nt fastest: A L2-reuse
    const int row0 = mt * 128, col0 = nt * 128;

    const int tid = threadIdx.x, wid = tid >> 6, lane = tid & 63;
    const int wm = wid >> 1, wn = wid & 1, l15 = lane & 15, kq = lane >> 4;

    // A staging: wave wid owns 1KB segs {s0, s0+1} of each 8KB A tile
    const int s0  = wid * 2;
    const int rA0 = s0 * 16 + (lane >> 2);
    const int rA1 = rA0 + 16;
    const int c0  = (lane & 3) ^ ((rA0 >> 1) & 3);
    const int c1  = (lane & 3) ^ ((rA1 >> 1) & 3);
    const _Float16* ga0 = Ah + (size_t)(row0 + rA0) * 512 + c0 * 8;
    const _Float16* ga1 = Ah + (size_t)(row0 + rA1) * 512 + c1 * 8;

    // W fragment base for this thread: frags at wfb + (ks*4+nf)*512
    const _Float16* wfb = Wf + (size_t)(nt * 2 + wn) * 32768 + lane * 8;

    f32x4 acc[4][4];
#pragma unroll
    for (int i = 0; i < 4; ++i)
#pragma unroll
        for (int j = 0; j < 4; ++j) acc[i][j] = (f32x4)0.f;

    half8 wfa[4], wfb_[4];   // two named W-frag sets (static indices only)

#define STAGE_A(KB, BUF)                                                       \
    do {                                                                       \
        _Float16* bdst = lds + (BUF) * 4096;                                   \
        gload_lds16(ga0 + (KB), bdst + s0 * 512);                              \
        gload_lds16(ga1 + (KB), bdst + (s0 + 1) * 512);                        \
    } while (0)

#define LOAD_W(DST, KS)                                                        \
    do {                                                                       \
        _Pragma("unroll")                                                      \
        for (int nf = 0; nf < 4; ++nf)                                         \
            DST[nf] = *reinterpret_cast<const half8*>(                         \
                wfb + (KS) * 2048 + nf * 512);                                 \
    } while (0)

#define FRAG_MFMA(BC, WU)                                                      \
    do {                                                                       \
        half8 ah[4];                                                           \
        _Pragma("unroll")                                                      \
        for (int mf = 0; mf < 4; ++mf) {                                       \
            const int r  = wm * 64 + mf * 16 + l15;                            \
            const int ph = (kq ^ ((r >> 1) & 3)) * 8;                          \
            ah[mf] = *reinterpret_cast<const half8*>((BC) + r * 32 + ph);      \
        }                                                                      \
        __builtin_amdgcn_s_setprio(1);                                         \
        _Pragma("unroll")                                                      \
        for (int nf = 0; nf < 4; ++nf)                                         \
            _Pragma("unroll")                                                  \
            for (int mf = 0; mf < 4; ++mf)                                     \
                acc[mf][nf] = __builtin_amdgcn_mfma_f32_16x16x32_f16(          \
                    ah[mf], WU[nf], acc[mf][nf], 0, 0, 0);                     \
        __builtin_amdgcn_s_setprio(0);                                         \
    } while (0)

// STEP(T): stage A tile T+2 (buffer cb+2), pin issue order, load other W set
// with tile T+1, compute tile T from buffer cb. Barrier: NO vmcnt — the
// wave's A(T+1) glds were passively drained by this FRAG's W(T)-register
// wait (in-order retirement), which precedes the barrier.
#define STEP(T, WU, WL)                                                        \
    do {                                                                       \
        const int t2 = ((T) + 2 < 16) ? (T) + 2 : 15;                          \
        const int t1 = ((T) + 1 < 16) ? (T) + 1 : 15;                          \
        int sb = cb + 2; if (sb >= 3) sb -= 3;                                 \
        STAGE_A(t2 * 32, sb);                                                  \
        __builtin_amdgcn_sched_barrier(0);   /* pin: A glds before W loads */  \
        LOAD_W(WL, t1);                                                        \
        FRAG_MFMA(lds + cb * 4096, WU);                                        \
        __builtin_amdgcn_sched_barrier(0);                                     \
        __builtin_amdgcn_s_barrier();                                          \
        __builtin_amdgcn_sched_barrier(0);                                     \
        cb = (cb == 2) ? 0 : cb + 1;                                           \
    } while (0)

    // prologue: A tiles 0,1 -> bufs 0,1; W set a <- tile 0; drain A only
    STAGE_A(0, 0);
    STAGE_A(32, 1);
    __builtin_amdgcn_sched_barrier(0);
    LOAD_W(wfa, 0);
    asm volatile("s_waitcnt vmcnt(4)" ::: "memory");   // A(0),A(1) landed
    __builtin_amdgcn_sched_barrier(0);
    __builtin_amdgcn_s_barrier();
    __builtin_amdgcn_sched_barrier(0);

    int cb = 0;
#pragma unroll 1
    for (int t = 0; t < 16; t += 2) {
        STEP(t,     wfa, wfb_);
        STEP(t + 1, wfb_, wfa);
    }
#undef STEP
#undef FRAG_MFMA
#undef LOAD_W
#undef STAGE_A

    // ---- epilogue: per-wave LDS transpose -> fp16 half4 stores.
    // __syncthreads() fences between scatter and gather (r17-verified).
    float* wbase = reinterpret_cast<float*>(lds) + wid * 1088;
    const float4 bv4 = *reinterpret_cast<const float4*>(
        &bias[col0 + wn * 64 + l15 * 4]);

#pragma unroll
    for (int mf = 0; mf < 4; ++mf) {
#pragma unroll
        for (int nf = 0; nf < 4; ++nf)
#pragma unroll
            for (int j = 0; j < 4; ++j)
                wbase[(kq * 4 + j) * 68 + nf * 16 + l15] = acc[mf][nf][j];
        __syncthreads();   // writes visible before cross-lane reads
#pragma unroll
        for (int i = 0; i < 4; ++i) {
            const int r16 = i * 4 + kq;
            float4 v = *reinterpret_cast<float4*>(wbase + r16 * 68 + l15 * 4);
            half4 h;
            h[0] = (_Float16)(v.x + bv4.x);   // RNE
            h[1] = (_Float16)(v.y + bv4.y);
            h[2] = (_Float16)(v.z + bv4.z);
            h[3] = (_Float16)(v.w + bv4.w);
            const int r = row0 + wm * 64 + mf * 16 + r16;
            *reinterpret_cast<half4*>(
                &C[(size_t)r * 1536 + col0 + wn * 64 + l15 * 4]) = h;
        }
        __syncthreads();   // reads done before next mf's scatter overwrites
    }
}

// ---------------------------------------------------------------------------
// k2: scrambled elementwise softmax; qkv FP16 (r18-verified)
// ---------------------------------------------------------------------------
__global__ __launch_bounds__(256) void attn_scramble(
    const _Float16* __restrict__ qkv, float* __restrict__ out)
{
    __shared__ float Ks[64][68];    // [hwlo][d'], rows 272B (16B-aligned)
    const int bid = blockIdx.x;
    const int hw6 = bid & 63;
    const int n   = (bid >> 6) & 7;
    const int b   = bid >> 9;
    const int kn  = (n + 7) & 7;
    const int t   = threadIdx.x;
    {
        const int lx = t & 7;       // 8 lanes x half8 cover one d'-row (64)
        const int rp = t >> 3;      // 32 d'-rows per pass
#pragma unroll
        for (int p = 0; p < 2; ++p) {
            const int dp = p * 32 + rp;
            const half8 kv = *reinterpret_cast<const half8*>(
                &qkv[(size_t)(b * 4096 + dp * 64 + hw6) * 1536 + 512 +
                     kn * 64 + lx * 8]);
#pragma unroll
            for (int e = 0; e < 8; ++e)
                Ks[lx * 8 + e][dp] = (float)kv[e];
        }
    }
    __syncthreads();
    const int row = t >> 2;
    const int tl  = t & 3;
    const size_t rbase = (size_t)(b * 4096 + hw6 * 64 + row) * 1536;
    float s[16];
    {
        const _Float16* qp = qkv + rbase + n * 64 + tl * 16;
        const half8 q0 = *reinterpret_cast<const half8*>(qp);
        const half8 q1 = *reinterpret_cast<const half8*>(qp + 8);
        float q[16], kk[16];
#pragma unroll
        for (int e = 0; e < 8; ++e) {
            q[e] = (float)q0[e];
            q[8 + e] = (float)q1[e];
        }
#pragma unroll
        for (int u = 0; u < 4; ++u)
            *reinterpret_cast<float4*>(&kk[u * 4]) =
                *reinterpret_cast<const float4*>(&Ks[row][tl * 16 + u * 4]);
        float m = -1e30f;
#pragma unroll
        for (int u = 0; u < 16; ++u) {
            s[u] = 0.125f * q[u] * kk[u];
            m = fmaxf(m, s[u]);
        }
        m = fmaxf(m, __shfl_xor(m, 1));
        m = fmaxf(m, __shfl_xor(m, 2));
        float sum = 0.f;
#pragma unroll
        for (int u = 0; u < 16; ++u) {
            s[u] = __expf(s[u] - m);
            sum += s[u];
        }
        sum += __shfl_xor(sum, 1);
        sum += __shfl_xor(sum, 2);
        const float inv = 1.0f / sum;
#pragma unroll
        for (int u = 0; u < 16; ++u) s[u] *= inv;
    }
    const _Float16* vp = qkv + rbase + 1024 + kn * 64 + tl * 16;
    const half8 v0 = *reinterpret_cast<const half8*>(vp);
    const half8 v1 = *reinterpret_cast<const half8*>(vp + 8);
    const int vb = b >> 3, fr = b & 7;
    float* op = out +
        ((size_t)(((vb * 8 + (hw6 >> 3)) * 64 + ((hw6 & 7) * 8 + (row >> 3))) * 64 +
                  ((row & 7) * 8 + n)) * 512) + fr * 64 + tl * 16;
    float4 o0, o1, o2, o3;
    o0.x = s[0]  * (float)v0[0]; o0.y = s[1]  * (float)v0[1];
    o0.z = s[2]  * (float)v0[2]; o0.w = s[3]  * (float)v0[3];
    o1.x = s[4]  * (float)v0[4]; o1.y = s[5]  * (float)v0[5];
    o1.z = s[6]  * (float)v0[6]; o1.w = s[7]  * (float)v0[7];
    o2.x = s[8]  * (float)v1[0]; o2.y = s[9]  * (float)v1[1];
    o2.z = s[10] * (float)v1[2]; o2.w = s[11] * (float)v1[3];
    o3.x = s[12] * (float)v1[4]; o3.y = s[13] * (float)v1[5];
    o3.z = s[14] * (float)v1[6]; o3.w = s[15] * (float)v1[7];
    *reinterpret_cast<float4*>(op)      = o0;
    *reinterpret_cast<float4*>(op + 4)  = o1;
    *reinterpret_cast<float4*>(op + 8)  = o2;
    *reinterpret_cast<float4*>(op + 12) = o3;
}

// ---------------------------------------------------------------------------
extern "C" void kernel_launch(void* const* d_in, const int* in_sizes, int n_in,
                              void* d_out, int out_size, void* d_ws, size_t ws_size,
                              hipStream_t stream) {
    const float* hs = (const float*)d_in[0];  // [65536,512]
    const float* w  = (const float*)d_in[1];  // [1536,512]
    const float* bq = (const float*)d_in[2];  // [1536]
    float* out = (float*)d_out;
    _Float16* qkv = (_Float16*)d_ws;          // 201,326,592 B (fits)

    // d_out as scratch: Ah (67,108,864 B) | Wf (1,572,864 B)
    _Float16* Asp = (_Float16*)d_out;
    _Float16* Wf  = Asp + 33554432;           // 65536*512

    cvt_fp16<<<16384, 256, 0, stream>>>(hs, Asp);
    cvt_w_frag<<<384, 256, 0, stream>>>(w, Wf);
    gemm_qkv_wf<<<6144, 256, 0, stream>>>(Asp, Wf, bq, qkv);
    attn_scramble<<<8192, 256, 0, stream>>>(qkv, out);
}